// Round 4
// baseline (482.607 us; speedup 1.0000x reference)
//
#include <hip/hip_runtime.h>

#define B 128
#define S 200
#define LW 50
#define Q 20
#define V 50000
#define D 128
#define NH 3
#define VD (V * D)              // 6,400,000
#define BSD (B * S * D)        // 3,276,800
#define BS (B * S)             // 25,600

typedef __bf16 bf16x8 __attribute__((ext_vector_type(8)));
typedef float f32x4 __attribute__((ext_vector_type(4)));

// ---- bf16 helpers (bit-level, RNE pack) -----------------------------------
__device__ __forceinline__ unsigned int f2bf_rne(float f) {
  union { float f; unsigned int u; } c; c.f = f;
  return (c.u + 0x7FFFu + ((c.u >> 16) & 1u)) >> 16;
}
__device__ __forceinline__ unsigned int pack2(float a, float b) {
  return f2bf_rne(a) | (f2bf_rne(b) << 16);
}
__device__ __forceinline__ float bf_lo(unsigned int q) {
  union { unsigned int u; float f; } c; c.u = q << 16; return c.f;
}
__device__ __forceinline__ float bf_hi(unsigned int q) {
  union { unsigned int u; float f; } c; c.u = q & 0xFFFF0000u; return c.f;
}

// ---------------------------------------------------------------------------
// Repack f32 tables -> slice-major bf16:
//   ESM[(k*4 + s)*V + v][c] (uint, c=0..15), slice s = d in [32s, 32s+32).
// Each (k,s) region is V*64B = 3.2 MB contiguous -> one XCD's L2 can hold it.
// Slice s of table 3 is also exactly MFMA k-chunk kk=s for the logits GEMM.
// ---------------------------------------------------------------------------
__global__ __launch_bounds__(256) void k_repack(
    const float* __restrict__ embs, unsigned int* __restrict__ ESM) {
  int v = blockIdx.x * 4 + (threadIdx.x >> 6);
  int l = threadIdx.x & 63;     // uint index within row: slice s=l>>4, c=l&15
  int s = l >> 4, c = l & 15;
#pragma unroll
  for (int k = 0; k < 4; ++k) {
    const float2 e = *(const float2*)(embs + (size_t)k * VD + (size_t)v * D + 2 * l);
    ESM[((size_t)(k * 4 + s) * V + v) * 16 + c] = pack2(e.x, e.y);
  }
}

// ---------------------------------------------------------------------------
// XCD-slice-partitioned story gather, one phase = 2 tables (2p, 2p+1).
// Block bi owns unit = bi&7 -> (k_local, slice); dispatch round-robin puts
// unit u on XCD u, so each XCD re-reads only its own 3.2 MB ESM region (L2-
// resident). Indices and G go non-temporal so streams don't evict the slice.
// 16 lanes per sentence; lane owns uint c (d = 32s+2c, 32s+2c+1).
// ---------------------------------------------------------------------------
__global__ __launch_bounds__(256) void k_gather_slice(
    const int* __restrict__ story, const unsigned int* __restrict__ ESM,
    unsigned int* __restrict__ Gp, int phase) {
  int unit = blockIdx.x & 7;
  int k = 2 * phase + (unit >> 2);
  int s = unit & 3;
  int wi = blockIdx.x >> 3;        // 0..255
  int grp = threadIdx.x >> 4;      // sentence group 0..15
  int c = threadIdx.x & 15;
  const unsigned int* src = ESM + (size_t)(k * 4 + s) * V * 16;
  int d0 = s * 32 + 2 * c;
  float c0 = (float)(d0 + 1) * (1.0f / D);
  float c1 = (float)(d0 + 2) * (1.0f / D);
  int sbase = wi * (BS / 256);     // 100 sentences per wi
  for (int t = grp; t < BS / 256; t += 16) {
    int sent = sbase + t;
    const int* w = story + sent * LW;
    float a0 = 0.f, a1 = 0.f;
#pragma unroll 2
    for (int j = 0; j < LW; ++j) {
      int idx = __builtin_nontemporal_load(w + j);
      float jj = (float)(j + 1) * (1.0f / LW);
      float al = 1.0f - jj;
      float bl = -(1.0f - 2.0f * jj);
      unsigned int q = src[(size_t)idx * 16 + c];
      a0 += bf_lo(q) * (al + bl * c0);
      a1 += bf_hi(q) * (al + bl * c1);
    }
    __builtin_nontemporal_store(
        pack2(a0, a1), Gp + ((size_t)k * BS + sent) * 64 + s * 16 + c);
  }
}

// ---------------------------------------------------------------------------
// Fused: query gather (f32 embs[0]) -> 3 hops over slice-major bf16 G ->
// u packed to bf16 for the MFMA logits. One block per b, 256 threads.
// G row d-mapping: uint index u -> d0 = (u>>4)*32 + (u&15)*2.
// ---------------------------------------------------------------------------
__global__ __launch_bounds__(256) void k_hops(
    const unsigned int* __restrict__ G, const int* __restrict__ query,
    const float* __restrict__ emb0, const float* __restrict__ TA,
    const float* __restrict__ TC, unsigned int* __restrict__ ubf) {
  __shared__ float su[D];
  __shared__ float sp[S];
  __shared__ float sred[2];
  __shared__ float4 oacc[8][32];
  int b = blockIdx.x;
  int t = threadIdx.x;
  if (t < D) {
    float kd = (float)(t + 1) * (1.0f / D);
    float acc = 0.f;
    for (int q = 0; q < Q; ++q) {
      int idx = query[b * Q + q];
      float jj = (float)(q + 1) * (1.0f / Q);
      float pe = 1.0f - jj - kd * (1.0f - 2.0f * jj);
      acc += emb0[(size_t)idx * D + t] * pe;
    }
    su[t] = acc;
  }
  __syncthreads();
  for (int hop = 0; hop < NH; ++hop) {
    const unsigned int* Gm = G + ((size_t)hop * BS + (size_t)b * S) * 64;
    const unsigned int* Gc = G + ((size_t)(hop + 1) * BS + (size_t)b * S) * 64;
    const float* ta = TA + hop * S * D;
    const float* tc = TC + hop * S * D;
    if (t < S) {
      float sc = 0.f;
#pragma unroll
      for (int s4 = 0; s4 < 4; ++s4)
#pragma unroll
        for (int i = 0; i < 8; ++i) {
          uint2 g2 = *(const uint2*)(Gm + (size_t)t * 64 + s4 * 16 + 2 * i);
          int d0 = s4 * 32 + 4 * i;
          float4 t4 = *(const float4*)(ta + (size_t)t * D + d0);
          sc += (bf_lo(g2.x) + t4.x) * su[d0 + 0];
          sc += (bf_hi(g2.x) + t4.y) * su[d0 + 1];
          sc += (bf_lo(g2.y) + t4.z) * su[d0 + 2];
          sc += (bf_hi(g2.y) + t4.w) * su[d0 + 3];
        }
      sp[t] = sc;
    }
    __syncthreads();
    if (t < 64) {
      float mx = -1e30f;
      for (int s = t; s < S; s += 64) mx = fmaxf(mx, sp[s]);
#pragma unroll
      for (int off = 1; off < 64; off <<= 1) mx = fmaxf(mx, __shfl_xor(mx, off));
      float sum = 0.f;
      for (int s = t; s < S; s += 64) sum += expf(sp[s] - mx);
#pragma unroll
      for (int off = 1; off < 64; off <<= 1) sum += __shfl_xor(sum, off);
      if (t == 0) { sred[0] = mx; sred[1] = sum; }
    }
    __syncthreads();
    float mx = sred[0];
    float inv = 1.0f / sred[1];
    if (t < S) sp[t] = expf(sp[t] - mx) * inv;
    __syncthreads();
    {
      int g = t >> 5, c = t & 31;
      int d0 = (c >> 3) * 32 + (c & 7) * 4;    // uint pair 2c -> d0
      float4 o4 = {0.f, 0.f, 0.f, 0.f};
      for (int s = g; s < S; s += 8) {
        float p = sp[s];
        uint2 g2 = *(const uint2*)(Gc + (size_t)s * 64 + 2 * c);
        float4 t4 = *(const float4*)(tc + (size_t)s * D + d0);
        o4.x += p * (bf_lo(g2.x) + t4.x);
        o4.y += p * (bf_hi(g2.x) + t4.y);
        o4.z += p * (bf_lo(g2.y) + t4.z);
        o4.w += p * (bf_hi(g2.y) + t4.w);
      }
      oacc[g][c] = o4;
    }
    __syncthreads();
    if (t < 32) {
      int d0 = (t >> 3) * 32 + (t & 7) * 4;
      float4 o = oacc[0][t];
#pragma unroll
      for (int g = 1; g < 8; ++g) {
        float4 x = oacc[g][t];
        o.x += x.x; o.y += x.y; o.z += x.z; o.w += x.w;
      }
      su[d0 + 0] += o.x;
      su[d0 + 1] += o.y;
      su[d0 + 2] += o.z;
      su[d0 + 3] += o.w;
    }
    __syncthreads();
  }
  if (t < 64) ubf[b * 64 + t] = pack2(su[2 * t], su[2 * t + 1]);
}

// ---------------------------------------------------------------------------
// logits[b][v] = sum_d u[b][d] * e3[v][d] via mfma_f32_16x16x32_bf16.
// B-frag reads slice-major ESM table 3 directly: k-chunk kk == slice kk.
// ---------------------------------------------------------------------------
__global__ __launch_bounds__(256) void k_logits_mfma(
    const uint4* __restrict__ ubf,   // [B][16] uint4 (row-major d)
    const uint4* __restrict__ esm,   // slice-major, uint4 granularity
    float* __restrict__ out) {
  int wid = threadIdx.x >> 6;
  int l = threadIdx.x & 63;
  int lr = l & 15;
  int lk = l >> 4;
  int vbase = blockIdx.x * 128 + wid * 32;
  uint4 bfrag[2][4];
#pragma unroll
  for (int vs = 0; vs < 2; ++vs) {
    int v = vbase + vs * 16 + lr;
    if (v >= V) v = V - 1;  // clamp loads; stores guarded
#pragma unroll
    for (int kk = 0; kk < 4; ++kk)
      bfrag[vs][kk] = esm[((size_t)(12 + kk) * V + v) * 4 + lk];
  }
  f32x4 acc[2][8];
#pragma unroll
  for (int vs = 0; vs < 2; ++vs)
#pragma unroll
    for (int m = 0; m < 8; ++m) {
      f32x4 z = {0.f, 0.f, 0.f, 0.f};
      acc[vs][m] = z;
    }
#pragma unroll
  for (int m = 0; m < 8; ++m) {
    uint4 afrag[4];
#pragma unroll
    for (int kk = 0; kk < 4; ++kk)
      afrag[kk] = ubf[(m * 16 + lr) * 16 + kk * 4 + lk];
#pragma unroll
    for (int vs = 0; vs < 2; ++vs)
#pragma unroll
      for (int kk = 0; kk < 4; ++kk)
        acc[vs][m] = __builtin_amdgcn_mfma_f32_16x16x32_bf16(
            __builtin_bit_cast(bf16x8, afrag[kk]),
            __builtin_bit_cast(bf16x8, bfrag[vs][kk]), acc[vs][m], 0, 0, 0);
  }
#pragma unroll
  for (int vs = 0; vs < 2; ++vs) {
    int v = vbase + vs * 16 + lr;
    if (v < V) {
#pragma unroll
      for (int m = 0; m < 8; ++m)
#pragma unroll
        for (int r = 0; r < 4; ++r)
          out[(size_t)(m * 16 + lk * 4 + r) * V + v] = acc[vs][m][r];
    }
  }
}

// ---------------------------------------------------------------------------
// Round-1 f32 fallback kernels (used only if ws too small)
// ---------------------------------------------------------------------------
__global__ __launch_bounds__(128) void k_gather_query(
    const int* __restrict__ query, const float* __restrict__ embs,
    float* __restrict__ u) {
  int b = blockIdx.x;
  int d = threadIdx.x;
  float kd = (float)(d + 1) / (float)D;
  float acc = 0.f;
  for (int q = 0; q < Q; ++q) {
    int idx = query[b * Q + q];
    float jj = (float)(q + 1) / (float)Q;
    float pe = 1.0f - jj - kd * (1.0f - 2.0f * jj);
    acc += embs[(size_t)idx * D + d] * pe;
  }
  u[b * D + d] = acc;
}

__global__ __launch_bounds__(128) void k_gather_story(
    const int* __restrict__ story, const float* __restrict__ embs,
    float* __restrict__ G) {
  int bs = blockIdx.x;
  int d = threadIdx.x;
  const int* w = story + bs * LW;
  float kd = (float)(d + 1) / (float)D;
  float a0 = 0.f, a1 = 0.f, a2 = 0.f, a3 = 0.f;
  for (int l = 0; l < LW; ++l) {
    int idx = w[l];
    float jj = (float)(l + 1) / (float)LW;
    float pe = 1.0f - jj - kd * (1.0f - 2.0f * jj);
    size_t base = (size_t)idx * D + d;
    a0 += embs[base] * pe;
    a1 += embs[base + (size_t)VD] * pe;
    a2 += embs[base + (size_t)(2 * VD)] * pe;
    a3 += embs[base + (size_t)(3 * VD)] * pe;
  }
  size_t o = (size_t)bs * D + d;
  G[o] = a0;
  G[o + (size_t)BSD] = a1;
  G[o + (size_t)(2 * BSD)] = a2;
  G[o + (size_t)(3 * BSD)] = a3;
}

__global__ __launch_bounds__(256) void k_hops_f32(
    const float* __restrict__ G, const float* __restrict__ TA,
    const float* __restrict__ TC, float* __restrict__ u) {
  __shared__ float su[D];
  __shared__ float sp[S];
  __shared__ float sred[2];
  int b = blockIdx.x;
  int t = threadIdx.x;
  if (t < D) su[t] = u[b * D + t];
  __syncthreads();
  for (int hop = 0; hop < NH; ++hop) {
    const float* Gm = G + (size_t)hop * BSD + (size_t)b * S * D;
    const float* Gc = G + (size_t)(hop + 1) * BSD + (size_t)b * S * D;
    const float* ta = TA + hop * S * D;
    const float* tc = TC + hop * S * D;
    if (t < S) {
      float sc = 0.f;
      for (int d = 0; d < D; ++d) sc += (Gm[t * D + d] + ta[t * D + d]) * su[d];
      sp[t] = sc;
    }
    __syncthreads();
    if (t < 64) {
      float mx = -1e30f;
      for (int s = t; s < S; s += 64) mx = fmaxf(mx, sp[s]);
#pragma unroll
      for (int off = 1; off < 64; off <<= 1) mx = fmaxf(mx, __shfl_xor(mx, off));
      float sum = 0.f;
      for (int s = t; s < S; s += 64) sum += expf(sp[s] - mx);
#pragma unroll
      for (int off = 1; off < 64; off <<= 1) sum += __shfl_xor(sum, off);
      if (t == 0) { sred[0] = mx; sred[1] = sum; }
    }
    __syncthreads();
    float mx = sred[0];
    float inv = 1.0f / sred[1];
    if (t < S) sp[t] = expf(sp[t] - mx) * inv;
    __syncthreads();
    if (t < D) {
      float o = 0.f;
      for (int s = 0; s < S; ++s) o += sp[s] * (Gc[s * D + t] + tc[s * D + t]);
      su[t] += o;
    }
    __syncthreads();
  }
  if (t < D) u[b * D + t] = su[t];
}

__global__ __launch_bounds__(256) void k_logits_f32(
    const float* __restrict__ u, const float* __restrict__ e3,
    float* __restrict__ out) {
  __shared__ float sE[64][129];
  __shared__ float sU[64][129];
  int v0 = blockIdx.x * 64;
  int b0 = blockIdx.y * 64;
  int t = threadIdx.x;
  for (int i = 0; i < 32; ++i) {
    int lin = i * 256 + t;
    int r = lin >> 7, c = lin & 127;
    int v = v0 + r;
    sE[r][c] = (v < V) ? e3[(size_t)v * D + c] : 0.f;
    sU[r][c] = u[(b0 + r) * D + c];
  }
  __syncthreads();
  int tv = (t & 15) * 4;
  int tb = (t >> 4) * 4;
  float acc[4][4] = {};
  for (int d = 0; d < D; ++d) {
    float ev[4], ub[4];
#pragma unroll
    for (int i = 0; i < 4; ++i) ev[i] = sE[tv + i][d];
#pragma unroll
    for (int j = 0; j < 4; ++j) ub[j] = sU[tb + j][d];
#pragma unroll
    for (int j = 0; j < 4; ++j)
#pragma unroll
      for (int i = 0; i < 4; ++i) acc[j][i] += ub[j] * ev[i];
  }
  for (int j = 0; j < 4; ++j)
    for (int i = 0; i < 4; ++i) {
      int v = v0 + tv + i;
      if (v < V) out[(size_t)(b0 + tb + j) * V + v] = acc[j][i];
    }
}

extern "C" void kernel_launch(void* const* d_in, const int* in_sizes, int n_in,
                              void* d_out, int out_size, void* d_ws,
                              size_t ws_size, hipStream_t stream) {
  (void)in_sizes; (void)n_in; (void)out_size;
  const int* story = (const int*)d_in[0];
  const int* query = (const int*)d_in[1];
  const float* embs = (const float*)d_in[2];
  const float* TA = (const float*)d_in[3];
  const float* TC = (const float*)d_in[4];
  float* out = (float*)d_out;

  const size_t esm_bytes = (size_t)16 * V * 16 * 4;              // 51.2 MB
  const size_t g_bytes = (size_t)4 * BS * 64 * 4;                // 26.2 MB
  const size_t ub_bytes = (size_t)B * 64 * 4;                    // 32 KB

  if (ws_size >= esm_bytes + g_bytes + ub_bytes) {
    char* p = (char*)d_ws;
    unsigned int* ESM = (unsigned int*)p;  p += esm_bytes;
    unsigned int* Gp = (unsigned int*)p;   p += g_bytes;
    unsigned int* ubf = (unsigned int*)p;

    k_repack<<<V / 4, 256, 0, stream>>>(embs, ESM);
    k_gather_slice<<<2048, 256, 0, stream>>>(story, ESM, Gp, 0);
    k_gather_slice<<<2048, 256, 0, stream>>>(story, ESM, Gp, 1);
    k_hops<<<B, 256, 0, stream>>>(Gp, query, embs, TA, TC, ubf);
    k_logits_mfma<<<(V + 127) / 128, 256, 0, stream>>>(
        (const uint4*)ubf, (const uint4*)ESM, out);
  } else {
    float* G = (float*)d_ws;
    float* u = G + 4 * (size_t)BSD;
    k_gather_query<<<B, D, 0, stream>>>(query, embs, u);
    k_gather_story<<<B * S, D, 0, stream>>>(story, embs, G);
    k_hops_f32<<<B, 256, 0, stream>>>(G, TA, TC, u);
    k_logits_f32<<<dim3((V + 63) / 64, B / 64), 256, 0, stream>>>(
        u, embs + 3 * (size_t)VD, out);
  }
}

// Round 6
// 208.471 us; speedup vs baseline: 2.3150x; 2.3150x over previous
//
#include <hip/hip_runtime.h>

#define B 128
#define S 200
#define LW 50
#define Q 20
#define V 50000
#define D 128
#define NH 3
#define VD (V * D)              // 6,400,000
#define BSD (B * S * D)        // 3,276,800
#define BS (B * S)             // 25,600

typedef __bf16 bf16x8 __attribute__((ext_vector_type(8)));
typedef float f32x4 __attribute__((ext_vector_type(4)));
typedef unsigned int u32x4 __attribute__((ext_vector_type(4)));

// ---- bf16 helpers (bit-level, RNE pack) -----------------------------------
__device__ __forceinline__ unsigned int f2bf_rne(float f) {
  union { float f; unsigned int u; } c; c.f = f;
  return (c.u + 0x7FFFu + ((c.u >> 16) & 1u)) >> 16;
}
__device__ __forceinline__ unsigned int pack2(float a, float b) {
  return f2bf_rne(a) | (f2bf_rne(b) << 16);
}
__device__ __forceinline__ float bf_lo(unsigned int q) {
  union { unsigned int u; float f; } c; c.u = q << 16; return c.f;
}
__device__ __forceinline__ float bf_hi(unsigned int q) {
  union { unsigned int u; float f; } c; c.u = q & 0xFFFF0000u; return c.f;
}

// ---------------------------------------------------------------------------
// Repack f32 tables -> slice-major bf16:
//   ESM[(k*4 + s)*V + v][c] (uint, c=0..15), slice s = d in [32s, 32s+32).
// Each (k,s) region is V*64B = 3.2 MB contiguous -> fits one XCD's 4MB L2.
// Slice s of table 3 is also exactly MFMA k-chunk kk=s for the logits GEMM.
// ---------------------------------------------------------------------------
__global__ __launch_bounds__(256) void k_repack(
    const float* __restrict__ embs, unsigned int* __restrict__ ESM) {
  int v = blockIdx.x * 4 + (threadIdx.x >> 6);
  int l = threadIdx.x & 63;
  int s = l >> 4, c = l & 15;
#pragma unroll
  for (int k = 0; k < 4; ++k) {
    const float2 e = *(const float2*)(embs + (size_t)k * VD + (size_t)v * D + 2 * l);
    ESM[((size_t)(k * 4 + s) * V + v) * 16 + c] = pack2(e.x, e.y);
  }
}

// ---------------------------------------------------------------------------
// story (int32) -> story16 (uint16). V=50000 < 65536.
// ---------------------------------------------------------------------------
__global__ __launch_bounds__(256) void k_story16(
    const int* __restrict__ story, unsigned short* __restrict__ story16) {
  int i = blockIdx.x * 256 + threadIdx.x;     // 0 .. BS*LW/4 - 1
  int4 v = ((const int4*)story)[i];
  ushort4 o;
  o.x = (unsigned short)v.x; o.y = (unsigned short)v.y;
  o.z = (unsigned short)v.z; o.w = (unsigned short)v.w;
  ((ushort4*)story16)[i] = o;
}

// ---------------------------------------------------------------------------
// XCD-slice-partitioned gather, pipelined. Phase p covers tables {2p, 2p+1}.
// Block bi: unit = bi&7 -> (k,slice); round-robin dispatch puts unit u on
// XCD u so each XCD re-reads only its own 3.2 MB ESM region (L2-resident).
// Wave structure: 16 sentences x 4 lanes; lane q loads uint4 (16B) of the
// 64B row -> 1 KB per wave-instruction, 16 rows in flight. Indices staged
// in LDS per wave (bulk coalesced), read by conflict-free broadcast.
// pe(j,d) = al_j + kd_d*bl_j  =>  accumulate SA,SB; G = SA + kd*SB.
// ---------------------------------------------------------------------------
__global__ __launch_bounds__(256) void k_gather_slice(
    const unsigned short* __restrict__ story16,
    const u32x4* __restrict__ ESM4, unsigned int* __restrict__ Gp, int phase) {
  __shared__ __align__(16) unsigned short sidx[4][800];   // [wave][16 sent x 50]
  int unit = blockIdx.x & 7;
  int k = 2 * phase + (unit >> 2);
  int s = unit & 3;
  int widx = blockIdx.x >> 3;          // 0..199
  int w = threadIdx.x >> 6;
  int l = threadIdx.x & 63;
  int g = l >> 2;                      // sentence slot 0..15
  int q = l & 3;                       // uint4 quarter of the 64B row
  const u32x4* src4 = ESM4 + (size_t)(k * 4 + s) * V * 4;   // row v: src4[v*4+q]
  int d0 = s * 32 + 8 * q;
  float kd[8];
#pragma unroll
  for (int i = 0; i < 8; ++i) kd[i] = (float)(d0 + i + 1) * (1.0f / D);

  for (int iter = 0; iter < 2; ++iter) {
    int sent16 = widx * 128 + w * 32 + iter * 16;   // 16 consecutive sentences
    // ---- stage 800 uint16 indices (1600B contiguous) into this wave's LDS
    const u32x4* st4 = (const u32x4*)(story16 + sent16 * LW);
    u32x4* dst4 = (u32x4*)sidx[w];
#pragma unroll
    for (int m = 0; m < 2; ++m) {
      int e = l + m * 64;
      if (e < 100) dst4[e] = __builtin_nontemporal_load(st4 + e);
    }
    const unsigned short* wrow = sidx[w] + g * LW;
    float SA[8] = {0.f, 0.f, 0.f, 0.f, 0.f, 0.f, 0.f, 0.f};
    float SB[8] = {0.f, 0.f, 0.f, 0.f, 0.f, 0.f, 0.f, 0.f};
#pragma unroll 10
    for (int j = 0; j < LW; ++j) {
      int idx = (int)wrow[j];
      u32x4 qv = src4[(size_t)idx * 4 + q];
      float jj = (float)(j + 1) * (1.0f / LW);
      float al = 1.0f - jj;
      float bl = 2.0f * jj - 1.0f;
      float ee[8];
      ee[0] = bf_lo(qv.x); ee[1] = bf_hi(qv.x);
      ee[2] = bf_lo(qv.y); ee[3] = bf_hi(qv.y);
      ee[4] = bf_lo(qv.z); ee[5] = bf_hi(qv.z);
      ee[6] = bf_lo(qv.w); ee[7] = bf_hi(qv.w);
#pragma unroll
      for (int i = 0; i < 8; ++i) { SA[i] += ee[i] * al; SB[i] += ee[i] * bl; }
    }
    int sent = sent16 + g;
    u32x4 og;
    og.x = pack2(SA[0] + kd[0] * SB[0], SA[1] + kd[1] * SB[1]);
    og.y = pack2(SA[2] + kd[2] * SB[2], SA[3] + kd[3] * SB[3]);
    og.z = pack2(SA[4] + kd[4] * SB[4], SA[5] + kd[5] * SB[5]);
    og.w = pack2(SA[6] + kd[6] * SB[6], SA[7] + kd[7] * SB[7]);
    __builtin_nontemporal_store(
        og, (u32x4*)(Gp + ((size_t)k * BS + sent) * 64 + s * 16) + q);
  }
}

// ---------------------------------------------------------------------------
// Fused: query gather (f32 embs[0]) -> 3 hops over slice-major bf16 G ->
// u packed to bf16. One block per b, 256 threads. (verified round 4)
// ---------------------------------------------------------------------------
__global__ __launch_bounds__(256) void k_hops(
    const unsigned int* __restrict__ G, const int* __restrict__ query,
    const float* __restrict__ emb0, const float* __restrict__ TA,
    const float* __restrict__ TC, unsigned int* __restrict__ ubf) {
  __shared__ float su[D];
  __shared__ float sp[S];
  __shared__ float sred[2];
  __shared__ float4 oacc[8][32];
  int b = blockIdx.x;
  int t = threadIdx.x;
  if (t < D) {
    float kd = (float)(t + 1) * (1.0f / D);
    float acc = 0.f;
    for (int q = 0; q < Q; ++q) {
      int idx = query[b * Q + q];
      float jj = (float)(q + 1) * (1.0f / Q);
      float pe = 1.0f - jj - kd * (1.0f - 2.0f * jj);
      acc += emb0[(size_t)idx * D + t] * pe;
    }
    su[t] = acc;
  }
  __syncthreads();
  for (int hop = 0; hop < NH; ++hop) {
    const unsigned int* Gm = G + ((size_t)hop * BS + (size_t)b * S) * 64;
    const unsigned int* Gc = G + ((size_t)(hop + 1) * BS + (size_t)b * S) * 64;
    const float* ta = TA + hop * S * D;
    const float* tc = TC + hop * S * D;
    if (t < S) {
      float sc = 0.f;
#pragma unroll
      for (int s4 = 0; s4 < 4; ++s4)
#pragma unroll
        for (int i = 0; i < 8; ++i) {
          uint2 g2 = *(const uint2*)(Gm + (size_t)t * 64 + s4 * 16 + 2 * i);
          int d0 = s4 * 32 + 4 * i;
          float4 t4 = *(const float4*)(ta + (size_t)t * D + d0);
          sc += (bf_lo(g2.x) + t4.x) * su[d0 + 0];
          sc += (bf_hi(g2.x) + t4.y) * su[d0 + 1];
          sc += (bf_lo(g2.y) + t4.z) * su[d0 + 2];
          sc += (bf_hi(g2.y) + t4.w) * su[d0 + 3];
        }
      sp[t] = sc;
    }
    __syncthreads();
    if (t < 64) {
      float mx = -1e30f;
      for (int s = t; s < S; s += 64) mx = fmaxf(mx, sp[s]);
#pragma unroll
      for (int off = 1; off < 64; off <<= 1) mx = fmaxf(mx, __shfl_xor(mx, off));
      float sum = 0.f;
      for (int s = t; s < S; s += 64) sum += expf(sp[s] - mx);
#pragma unroll
      for (int off = 1; off < 64; off <<= 1) sum += __shfl_xor(sum, off);
      if (t == 0) { sred[0] = mx; sred[1] = sum; }
    }
    __syncthreads();
    float mx = sred[0];
    float inv = 1.0f / sred[1];
    if (t < S) sp[t] = expf(sp[t] - mx) * inv;
    __syncthreads();
    {
      int g = t >> 5, c = t & 31;
      int d0 = (c >> 3) * 32 + (c & 7) * 4;
      float4 o4 = {0.f, 0.f, 0.f, 0.f};
      for (int s = g; s < S; s += 8) {
        float p = sp[s];
        uint2 g2 = *(const uint2*)(Gc + (size_t)s * 64 + 2 * c);
        float4 t4 = *(const float4*)(tc + (size_t)s * D + d0);
        o4.x += p * (bf_lo(g2.x) + t4.x);
        o4.y += p * (bf_hi(g2.x) + t4.y);
        o4.z += p * (bf_lo(g2.y) + t4.z);
        o4.w += p * (bf_hi(g2.y) + t4.w);
      }
      oacc[g][c] = o4;
    }
    __syncthreads();
    if (t < 32) {
      int d0 = (t >> 3) * 32 + (t & 7) * 4;
      float4 o = oacc[0][t];
#pragma unroll
      for (int g = 1; g < 8; ++g) {
        float4 x = oacc[g][t];
        o.x += x.x; o.y += x.y; o.z += x.z; o.w += x.w;
      }
      su[d0 + 0] += o.x;
      su[d0 + 1] += o.y;
      su[d0 + 2] += o.z;
      su[d0 + 3] += o.w;
    }
    __syncthreads();
  }
  if (t < 64) ubf[b * 64 + t] = pack2(su[2 * t], su[2 * t + 1]);
}

// ---------------------------------------------------------------------------
// logits via mfma_f32_16x16x32_bf16; B-frag straight from slice-major ESM
// (k-chunk kk == slice kk of table 3). (verified round 4)
// ---------------------------------------------------------------------------
__global__ __launch_bounds__(256) void k_logits_mfma(
    const uint4* __restrict__ ubf,   // [B][16] uint4 (row-major d)
    const uint4* __restrict__ esm,   // slice-major, uint4 granularity
    float* __restrict__ out) {
  int wid = threadIdx.x >> 6;
  int l = threadIdx.x & 63;
  int lr = l & 15;
  int lk = l >> 4;
  int vbase = blockIdx.x * 128 + wid * 32;
  uint4 bfrag[2][4];
#pragma unroll
  for (int vs = 0; vs < 2; ++vs) {
    int v = vbase + vs * 16 + lr;
    if (v >= V) v = V - 1;  // clamp loads; stores guarded
#pragma unroll
    for (int kk = 0; kk < 4; ++kk)
      bfrag[vs][kk] = esm[((size_t)(12 + kk) * V + v) * 4 + lk];
  }
  f32x4 acc[2][8];
#pragma unroll
  for (int vs = 0; vs < 2; ++vs)
#pragma unroll
    for (int m = 0; m < 8; ++m) {
      f32x4 z = {0.f, 0.f, 0.f, 0.f};
      acc[vs][m] = z;
    }
#pragma unroll
  for (int m = 0; m < 8; ++m) {
    uint4 afrag[4];
#pragma unroll
    for (int kk = 0; kk < 4; ++kk)
      afrag[kk] = ubf[(m * 16 + lr) * 16 + kk * 4 + lk];
#pragma unroll
    for (int vs = 0; vs < 2; ++vs)
#pragma unroll
      for (int kk = 0; kk < 4; ++kk)
        acc[vs][m] = __builtin_amdgcn_mfma_f32_16x16x32_bf16(
            __builtin_bit_cast(bf16x8, afrag[kk]),
            __builtin_bit_cast(bf16x8, bfrag[vs][kk]), acc[vs][m], 0, 0, 0);
  }
#pragma unroll
  for (int vs = 0; vs < 2; ++vs) {
    int v = vbase + vs * 16 + lr;
    if (v < V) {
#pragma unroll
      for (int m = 0; m < 8; ++m)
#pragma unroll
        for (int r = 0; r < 4; ++r)
          out[(size_t)(m * 16 + lk * 4 + r) * V + v] = acc[vs][m][r];
    }
  }
}

// ---------------------------------------------------------------------------
// Round-1 f32 fallback kernels (used only if ws too small)
// ---------------------------------------------------------------------------
__global__ __launch_bounds__(128) void k_gather_query(
    const int* __restrict__ query, const float* __restrict__ embs,
    float* __restrict__ u) {
  int b = blockIdx.x;
  int d = threadIdx.x;
  float kd = (float)(d + 1) / (float)D;
  float acc = 0.f;
  for (int q = 0; q < Q; ++q) {
    int idx = query[b * Q + q];
    float jj = (float)(q + 1) / (float)Q;
    float pe = 1.0f - jj - kd * (1.0f - 2.0f * jj);
    acc += embs[(size_t)idx * D + d] * pe;
  }
  u[b * D + d] = acc;
}

__global__ __launch_bounds__(128) void k_gather_story(
    const int* __restrict__ story, const float* __restrict__ embs,
    float* __restrict__ G) {
  int bs = blockIdx.x;
  int d = threadIdx.x;
  const int* w = story + bs * LW;
  float kd = (float)(d + 1) / (float)D;
  float a0 = 0.f, a1 = 0.f, a2 = 0.f, a3 = 0.f;
  for (int l = 0; l < LW; ++l) {
    int idx = w[l];
    float jj = (float)(l + 1) / (float)LW;
    float pe = 1.0f - jj - kd * (1.0f - 2.0f * jj);
    size_t base = (size_t)idx * D + d;
    a0 += embs[base] * pe;
    a1 += embs[base + (size_t)VD] * pe;
    a2 += embs[base + (size_t)(2 * VD)] * pe;
    a3 += embs[base + (size_t)(3 * VD)] * pe;
  }
  size_t o = (size_t)bs * D + d;
  G[o] = a0;
  G[o + (size_t)BSD] = a1;
  G[o + (size_t)(2 * BSD)] = a2;
  G[o + (size_t)(3 * BSD)] = a3;
}

__global__ __launch_bounds__(256) void k_hops_f32(
    const float* __restrict__ G, const float* __restrict__ TA,
    const float* __restrict__ TC, float* __restrict__ u) {
  __shared__ float su[D];
  __shared__ float sp[S];
  __shared__ float sred[2];
  int b = blockIdx.x;
  int t = threadIdx.x;
  if (t < D) su[t] = u[b * D + t];
  __syncthreads();
  for (int hop = 0; hop < NH; ++hop) {
    const float* Gm = G + (size_t)hop * BSD + (size_t)b * S * D;
    const float* Gc = G + (size_t)(hop + 1) * BSD + (size_t)b * S * D;
    const float* ta = TA + hop * S * D;
    const float* tc = TC + hop * S * D;
    if (t < S) {
      float sc = 0.f;
      for (int d = 0; d < D; ++d) sc += (Gm[t * D + d] + ta[t * D + d]) * su[d];
      sp[t] = sc;
    }
    __syncthreads();
    if (t < 64) {
      float mx = -1e30f;
      for (int s = t; s < S; s += 64) mx = fmaxf(mx, sp[s]);
#pragma unroll
      for (int off = 1; off < 64; off <<= 1) mx = fmaxf(mx, __shfl_xor(mx, off));
      float sum = 0.f;
      for (int s = t; s < S; s += 64) sum += expf(sp[s] - mx);
#pragma unroll
      for (int off = 1; off < 64; off <<= 1) sum += __shfl_xor(sum, off);
      if (t == 0) { sred[0] = mx; sred[1] = sum; }
    }
    __syncthreads();
    float mx = sred[0];
    float inv = 1.0f / sred[1];
    if (t < S) sp[t] = expf(sp[t] - mx) * inv;
    __syncthreads();
    if (t < D) {
      float o = 0.f;
      for (int s = 0; s < S; ++s) o += sp[s] * (Gc[s * D + t] + tc[s * D + t]);
      su[t] += o;
    }
    __syncthreads();
  }
  if (t < D) u[b * D + t] = su[t];
}

__global__ __launch_bounds__(256) void k_logits_f32(
    const float* __restrict__ u, const float* __restrict__ e3,
    float* __restrict__ out) {
  __shared__ float sE[64][129];
  __shared__ float sU[64][129];
  int v0 = blockIdx.x * 64;
  int b0 = blockIdx.y * 64;
  int t = threadIdx.x;
  for (int i = 0; i < 32; ++i) {
    int lin = i * 256 + t;
    int r = lin >> 7, c = lin & 127;
    int v = v0 + r;
    sE[r][c] = (v < V) ? e3[(size_t)v * D + c] : 0.f;
    sU[r][c] = u[(b0 + r) * D + c];
  }
  __syncthreads();
  int tv = (t & 15) * 4;
  int tb = (t >> 4) * 4;
  float acc[4][4] = {};
  for (int d = 0; d < D; ++d) {
    float ev[4], ub[4];
#pragma unroll
    for (int i = 0; i < 4; ++i) ev[i] = sE[tv + i][d];
#pragma unroll
    for (int j = 0; j < 4; ++j) ub[j] = sU[tb + j][d];
#pragma unroll
    for (int j = 0; j < 4; ++j)
#pragma unroll
      for (int i = 0; i < 4; ++i) acc[j][i] += ub[j] * ev[i];
  }
  for (int j = 0; j < 4; ++j)
    for (int i = 0; i < 4; ++i) {
      int v = v0 + tv + i;
      if (v < V) out[(size_t)(b0 + tb + j) * V + v] = acc[j][i];
    }
}

extern "C" void kernel_launch(void* const* d_in, const int* in_sizes, int n_in,
                              void* d_out, int out_size, void* d_ws,
                              size_t ws_size, hipStream_t stream) {
  (void)in_sizes; (void)n_in; (void)out_size;
  const int* story = (const int*)d_in[0];
  const int* query = (const int*)d_in[1];
  const float* embs = (const float*)d_in[2];
  const float* TA = (const float*)d_in[3];
  const float* TC = (const float*)d_in[4];
  float* out = (float*)d_out;

  const size_t esm_bytes = (size_t)16 * V * 16 * 4;    // 51.2 MB
  const size_t g_bytes = (size_t)4 * BS * 64 * 4;      // 26.2 MB
  const size_t ub_bytes = (size_t)B * 64 * 4;          // 32 KB
  const size_t s16_bytes = (size_t)BS * LW * 2;        // 2.56 MB

  if (ws_size >= esm_bytes + g_bytes + ub_bytes + s16_bytes) {
    char* p = (char*)d_ws;
    unsigned int* ESM = (unsigned int*)p;      p += esm_bytes;
    unsigned int* Gp = (unsigned int*)p;       p += g_bytes;
    unsigned int* ubf = (unsigned int*)p;      p += ub_bytes;
    unsigned short* story16 = (unsigned short*)p;

    k_repack<<<V / 4, 256, 0, stream>>>(embs, ESM);
    k_story16<<<BS * LW / 4 / 256, 256, 0, stream>>>(story, story16);
    k_gather_slice<<<1600, 256, 0, stream>>>(story16, (const u32x4*)ESM, Gp, 0);
    k_gather_slice<<<1600, 256, 0, stream>>>(story16, (const u32x4*)ESM, Gp, 1);
    k_hops<<<B, 256, 0, stream>>>(Gp, query, embs, TA, TC, ubf);
    k_logits_mfma<<<(V + 127) / 128, 256, 0, stream>>>(
        (const uint4*)ubf, (const uint4*)ESM, out);
  } else {
    float* G = (float*)d_ws;
    float* u = G + 4 * (size_t)BSD;
    k_gather_query<<<B, D, 0, stream>>>(query, embs, u);
    k_gather_story<<<B * S, D, 0, stream>>>(story, embs, G);
    k_hops_f32<<<B, 256, 0, stream>>>(G, TA, TC, u);
    k_logits_f32<<<dim3((V + 63) / 64, B / 64), 256, 0, stream>>>(
        u, embs + 3 * (size_t)VD, out);
  }
}

// Round 7
// 170.959 us; speedup vs baseline: 2.8229x; 1.2194x over previous
//
#include <hip/hip_runtime.h>

#define B 128
#define S 200
#define LW 50
#define Q 20
#define V 50000
#define D 128
#define NH 3
#define VD (V * D)              // 6,400,000
#define BSD (B * S * D)        // 3,276,800
#define BS (B * S)             // 25,600

typedef __bf16 bf16x8 __attribute__((ext_vector_type(8)));
typedef float f32x4 __attribute__((ext_vector_type(4)));
typedef unsigned int u32x4 __attribute__((ext_vector_type(4)));

// ---- bf16 helpers (bit-level, RNE pack) -----------------------------------
__device__ __forceinline__ unsigned int f2bf_rne(float f) {
  union { float f; unsigned int u; } c; c.f = f;
  return (c.u + 0x7FFFu + ((c.u >> 16) & 1u)) >> 16;
}
__device__ __forceinline__ unsigned int pack2(float a, float b) {
  return f2bf_rne(a) | (f2bf_rne(b) << 16);
}
__device__ __forceinline__ float bf_lo(unsigned int q) {
  union { unsigned int u; float f; } c; c.u = q << 16; return c.f;
}
__device__ __forceinline__ float bf_hi(unsigned int q) {
  union { unsigned int u; float f; } c; c.u = q & 0xFFFF0000u; return c.f;
}

// ---------------------------------------------------------------------------
// Repack f32 tables -> slice-major bf16:
//   ESM[(k*4 + s)*V + v][c] (uint, c=0..15), slice s = d in [32s, 32s+32).
// Each (k,s) region is V*64B = 3.2 MB contiguous -> fits one XCD's 4MB L2.
// Slice s of table 3 is also exactly MFMA k-chunk kk=s for the logits GEMM.
// ---------------------------------------------------------------------------
__global__ __launch_bounds__(256) void k_repack(
    const float* __restrict__ embs, unsigned int* __restrict__ ESM) {
  int v = blockIdx.x * 4 + (threadIdx.x >> 6);
  int l = threadIdx.x & 63;
  int s = l >> 4, c = l & 15;
#pragma unroll
  for (int k = 0; k < 4; ++k) {
    const float2 e = *(const float2*)(embs + (size_t)k * VD + (size_t)v * D + 2 * l);
    ESM[((size_t)(k * 4 + s) * V + v) * 16 + c] = pack2(e.x, e.y);
  }
}

// ---------------------------------------------------------------------------
// story (int32) -> story16 (uint16). V=50000 < 65536.
// ---------------------------------------------------------------------------
__global__ __launch_bounds__(256) void k_story16(
    const int* __restrict__ story, unsigned short* __restrict__ story16) {
  int i = blockIdx.x * 256 + threadIdx.x;     // 0 .. BS*LW/4 - 1
  int4 v = ((const int4*)story)[i];
  ushort4 o;
  o.x = (unsigned short)v.x; o.y = (unsigned short)v.y;
  o.z = (unsigned short)v.z; o.w = (unsigned short)v.w;
  ((ushort4*)story16)[i] = o;
}

// ---------------------------------------------------------------------------
// TA/TC -> bf16 packed pairs in G's slice-major uint order:
//   Tp[(hop*S + s)*64 + u] = pack2(T[hop][s][d0], T[hop][s][d0+1]),
//   d0 = 32*(u>>4) + 2*(u&15).
// ---------------------------------------------------------------------------
__global__ __launch_bounds__(256) void k_packT(
    const float* __restrict__ TA, const float* __restrict__ TC,
    unsigned int* __restrict__ TAp, unsigned int* __restrict__ TCp) {
  int idx = blockIdx.x * 256 + threadIdx.x;   // 0 .. NH*S*64-1
  int row = idx >> 6;                          // hop*S + s
  int u = idx & 63;
  int d0 = 32 * (u >> 4) + 2 * (u & 15);
  const float2 a = *(const float2*)(TA + (size_t)row * D + d0);
  const float2 c = *(const float2*)(TC + (size_t)row * D + d0);
  TAp[idx] = pack2(a.x, a.y);
  TCp[idx] = pack2(c.x, c.y);
}

// ---------------------------------------------------------------------------
// XCD-slice-partitioned gather. Phase p covers tables {2p, 2p+1}.
// Block bi: unit = bi&7 -> (k,slice); round-robin dispatch puts unit u on
// XCD u so each XCD re-reads only its own 3.2 MB ESM region (L2-resident).
// Grid 3200 (12.5 blocks/CU -> 8 resident): one 16-sentence tile per wave.
// Wave: 16 sentences x 4 lanes; lane q loads uint4 (16B) of the 64B row.
// Indices staged in LDS per wave (bulk coalesced), read via broadcast.
// pe(j,d) = al_j + kd_d*bl_j  =>  accumulate SA,SB; G = SA + kd*SB.
// ---------------------------------------------------------------------------
__global__ __launch_bounds__(256) void k_gather_slice(
    const unsigned short* __restrict__ story16,
    const u32x4* __restrict__ ESM4, unsigned int* __restrict__ Gp, int phase) {
  __shared__ __align__(16) unsigned short sidx[4][800];   // [wave][16 sent x 50]
  int unit = blockIdx.x & 7;
  int k = 2 * phase + (unit >> 2);
  int s = unit & 3;
  int widx = blockIdx.x >> 3;          // 0..399
  int w = threadIdx.x >> 6;
  int l = threadIdx.x & 63;
  int g = l >> 2;                      // sentence slot 0..15
  int q = l & 3;                       // uint4 quarter of the 64B row
  const u32x4* src4 = ESM4 + (size_t)(k * 4 + s) * V * 4;   // row v: src4[v*4+q]
  int d0 = s * 32 + 8 * q;
  float kd[8];
#pragma unroll
  for (int i = 0; i < 8; ++i) kd[i] = (float)(d0 + i + 1) * (1.0f / D);

  int sent16 = widx * 64 + w * 16;     // 16 consecutive sentences
  // ---- stage 800 uint16 indices (1600B contiguous) into this wave's LDS
  const u32x4* st4 = (const u32x4*)(story16 + sent16 * LW);
  u32x4* dst4 = (u32x4*)sidx[w];
#pragma unroll
  for (int m = 0; m < 2; ++m) {
    int e = l + m * 64;
    if (e < 100) dst4[e] = __builtin_nontemporal_load(st4 + e);
  }
  const unsigned short* wrow = sidx[w] + g * LW;
  float SA[8] = {0.f, 0.f, 0.f, 0.f, 0.f, 0.f, 0.f, 0.f};
  float SB[8] = {0.f, 0.f, 0.f, 0.f, 0.f, 0.f, 0.f, 0.f};
#pragma unroll 10
  for (int j = 0; j < LW; ++j) {
    int idx = (int)wrow[j];
    u32x4 qv = src4[(size_t)idx * 4 + q];
    float jj = (float)(j + 1) * (1.0f / LW);
    float al = 1.0f - jj;
    float bl = 2.0f * jj - 1.0f;
    float ee[8];
    ee[0] = bf_lo(qv.x); ee[1] = bf_hi(qv.x);
    ee[2] = bf_lo(qv.y); ee[3] = bf_hi(qv.y);
    ee[4] = bf_lo(qv.z); ee[5] = bf_hi(qv.z);
    ee[6] = bf_lo(qv.w); ee[7] = bf_hi(qv.w);
#pragma unroll
    for (int i = 0; i < 8; ++i) { SA[i] += ee[i] * al; SB[i] += ee[i] * bl; }
  }
  int sent = sent16 + g;
  u32x4 og;
  og.x = pack2(SA[0] + kd[0] * SB[0], SA[1] + kd[1] * SB[1]);
  og.y = pack2(SA[2] + kd[2] * SB[2], SA[3] + kd[3] * SB[3]);
  og.z = pack2(SA[4] + kd[4] * SB[4], SA[5] + kd[5] * SB[5]);
  og.w = pack2(SA[6] + kd[6] * SB[6], SA[7] + kd[7] * SB[7]);
  __builtin_nontemporal_store(
      og, (u32x4*)(Gp + ((size_t)k * BS + sent) * 64 + s * 16) + q);
}

// ---------------------------------------------------------------------------
// Fused: query gather (f32 embs[0]) -> 3 hops (bf16 G + bf16 TAp/TCp) ->
// u packed to bf16. One block per b, 1024 threads (16 waves for latency
// hiding; this kernel is latency-bound at 128 blocks).
// Score: 4 threads/sentence (32 d each), shfl combine.
// Weighted: 32 groups x 32 cols, LDS tree combine.
// ---------------------------------------------------------------------------
__global__ __launch_bounds__(1024) void k_hops(
    const unsigned int* __restrict__ G, const unsigned int* __restrict__ TAp,
    const unsigned int* __restrict__ TCp, const int* __restrict__ query,
    const float* __restrict__ emb0, unsigned int* __restrict__ ubf) {
  __shared__ float su[D];
  __shared__ float sp[S];
  __shared__ float sred[2];
  __shared__ float4 oacc[32][32];
  int b = blockIdx.x;
  int t = threadIdx.x;
  if (t < D) {
    float kd = (float)(t + 1) * (1.0f / D);
    float acc = 0.f;
    for (int q = 0; q < Q; ++q) {
      int idx = query[b * Q + q];
      float jj = (float)(q + 1) * (1.0f / Q);
      float pe = 1.0f - jj - kd * (1.0f - 2.0f * jj);
      acc += emb0[(size_t)idx * D + t] * pe;
    }
    su[t] = acc;
  }
  __syncthreads();
  for (int hop = 0; hop < NH; ++hop) {
    const unsigned int* Gm = G + ((size_t)hop * BS + (size_t)b * S) * 64;
    const unsigned int* Gc = G + ((size_t)(hop + 1) * BS + (size_t)b * S) * 64;
    const unsigned int* ta = TAp + (size_t)hop * S * 64;
    const unsigned int* tc = TCp + (size_t)hop * S * 64;
    if (t < 4 * S) {
      int sl = t >> 2, p = t & 3;
      const uint2* gr = (const uint2*)(Gm + (size_t)sl * 64 + p * 16);
      const uint2* tr = (const uint2*)(ta + (size_t)sl * 64 + p * 16);
      float sc = 0.f;
#pragma unroll
      for (int i = 0; i < 8; ++i) {
        uint2 g2 = gr[i];
        uint2 t2 = tr[i];
        int dd = p * 32 + 4 * i;
        sc += (bf_lo(g2.x) + bf_lo(t2.x)) * su[dd + 0];
        sc += (bf_hi(g2.x) + bf_hi(t2.x)) * su[dd + 1];
        sc += (bf_lo(g2.y) + bf_lo(t2.y)) * su[dd + 2];
        sc += (bf_hi(g2.y) + bf_hi(t2.y)) * su[dd + 3];
      }
      sc += __shfl_xor(sc, 1);
      sc += __shfl_xor(sc, 2);
      if (p == 0) sp[sl] = sc;
    }
    __syncthreads();
    if (t < 64) {
      float mx = -1e30f;
      for (int s = t; s < S; s += 64) mx = fmaxf(mx, sp[s]);
#pragma unroll
      for (int off = 1; off < 64; off <<= 1) mx = fmaxf(mx, __shfl_xor(mx, off));
      float sum = 0.f;
      for (int s = t; s < S; s += 64) sum += expf(sp[s] - mx);
#pragma unroll
      for (int off = 1; off < 64; off <<= 1) sum += __shfl_xor(sum, off);
      if (t == 0) { sred[0] = mx; sred[1] = sum; }
    }
    __syncthreads();
    float mx = sred[0];
    float inv = 1.0f / sred[1];
    if (t < S) sp[t] = expf(sp[t] - mx) * inv;
    __syncthreads();
    {
      int g = t >> 5, c = t & 31;
      float4 o4 = {0.f, 0.f, 0.f, 0.f};
      for (int s = g; s < S; s += 32) {
        float p = sp[s];
        uint2 g2 = *(const uint2*)(Gc + (size_t)s * 64 + 2 * c);
        uint2 t2 = *(const uint2*)(tc + (size_t)s * 64 + 2 * c);
        o4.x += p * (bf_lo(g2.x) + bf_lo(t2.x));
        o4.y += p * (bf_hi(g2.x) + bf_hi(t2.x));
        o4.z += p * (bf_lo(g2.y) + bf_lo(t2.y));
        o4.w += p * (bf_hi(g2.y) + bf_hi(t2.y));
      }
      oacc[g][c] = o4;
    }
    __syncthreads();
    if (t < 32) {
      int d0 = (t >> 3) * 32 + (t & 7) * 4;
      float4 o = oacc[0][t];
#pragma unroll
      for (int g = 1; g < 32; ++g) {
        float4 x = oacc[g][t];
        o.x += x.x; o.y += x.y; o.z += x.z; o.w += x.w;
      }
      su[d0 + 0] += o.x;
      su[d0 + 1] += o.y;
      su[d0 + 2] += o.z;
      su[d0 + 3] += o.w;
    }
    __syncthreads();
  }
  if (t < 64) ubf[b * 64 + t] = pack2(su[2 * t], su[2 * t + 1]);
}

// ---------------------------------------------------------------------------
// logits via mfma_f32_16x16x32_bf16; B-frag straight from slice-major ESM
// (k-chunk kk == slice kk of table 3). (verified round 4)
// ---------------------------------------------------------------------------
__global__ __launch_bounds__(256) void k_logits_mfma(
    const uint4* __restrict__ ubf,   // [B][16] uint4 (row-major d)
    const uint4* __restrict__ esm,   // slice-major, uint4 granularity
    float* __restrict__ out) {
  int wid = threadIdx.x >> 6;
  int l = threadIdx.x & 63;
  int lr = l & 15;
  int lk = l >> 4;
  int vbase = blockIdx.x * 128 + wid * 32;
  uint4 bfrag[2][4];
#pragma unroll
  for (int vs = 0; vs < 2; ++vs) {
    int v = vbase + vs * 16 + lr;
    if (v >= V) v = V - 1;  // clamp loads; stores guarded
#pragma unroll
    for (int kk = 0; kk < 4; ++kk)
      bfrag[vs][kk] = esm[((size_t)(12 + kk) * V + v) * 4 + lk];
  }
  f32x4 acc[2][8];
#pragma unroll
  for (int vs = 0; vs < 2; ++vs)
#pragma unroll
    for (int m = 0; m < 8; ++m) {
      f32x4 z = {0.f, 0.f, 0.f, 0.f};
      acc[vs][m] = z;
    }
#pragma unroll
  for (int m = 0; m < 8; ++m) {
    uint4 afrag[4];
#pragma unroll
    for (int kk = 0; kk < 4; ++kk)
      afrag[kk] = ubf[(m * 16 + lr) * 16 + kk * 4 + lk];
#pragma unroll
    for (int vs = 0; vs < 2; ++vs)
#pragma unroll
      for (int kk = 0; kk < 4; ++kk)
        acc[vs][m] = __builtin_amdgcn_mfma_f32_16x16x32_bf16(
            __builtin_bit_cast(bf16x8, afrag[kk]),
            __builtin_bit_cast(bf16x8, bfrag[vs][kk]), acc[vs][m], 0, 0, 0);
  }
#pragma unroll
  for (int vs = 0; vs < 2; ++vs) {
    int v = vbase + vs * 16 + lr;
    if (v < V) {
#pragma unroll
      for (int m = 0; m < 8; ++m)
#pragma unroll
        for (int r = 0; r < 4; ++r)
          out[(size_t)(m * 16 + lk * 4 + r) * V + v] = acc[vs][m][r];
    }
  }
}

// ---------------------------------------------------------------------------
// Round-1 f32 fallback kernels (used only if ws too small)
// ---------------------------------------------------------------------------
__global__ __launch_bounds__(128) void k_gather_query(
    const int* __restrict__ query, const float* __restrict__ embs,
    float* __restrict__ u) {
  int b = blockIdx.x;
  int d = threadIdx.x;
  float kd = (float)(d + 1) / (float)D;
  float acc = 0.f;
  for (int q = 0; q < Q; ++q) {
    int idx = query[b * Q + q];
    float jj = (float)(q + 1) / (float)Q;
    float pe = 1.0f - jj - kd * (1.0f - 2.0f * jj);
    acc += embs[(size_t)idx * D + d] * pe;
  }
  u[b * D + d] = acc;
}

__global__ __launch_bounds__(128) void k_gather_story(
    const int* __restrict__ story, const float* __restrict__ embs,
    float* __restrict__ G) {
  int bs = blockIdx.x;
  int d = threadIdx.x;
  const int* w = story + bs * LW;
  float kd = (float)(d + 1) / (float)D;
  float a0 = 0.f, a1 = 0.f, a2 = 0.f, a3 = 0.f;
  for (int l = 0; l < LW; ++l) {
    int idx = w[l];
    float jj = (float)(l + 1) / (float)LW;
    float pe = 1.0f - jj - kd * (1.0f - 2.0f * jj);
    size_t base = (size_t)idx * D + d;
    a0 += embs[base] * pe;
    a1 += embs[base + (size_t)VD] * pe;
    a2 += embs[base + (size_t)(2 * VD)] * pe;
    a3 += embs[base + (size_t)(3 * VD)] * pe;
  }
  size_t o = (size_t)bs * D + d;
  G[o] = a0;
  G[o + (size_t)BSD] = a1;
  G[o + (size_t)(2 * BSD)] = a2;
  G[o + (size_t)(3 * BSD)] = a3;
}

__global__ __launch_bounds__(256) void k_hops_f32(
    const float* __restrict__ G, const float* __restrict__ TA,
    const float* __restrict__ TC, float* __restrict__ u) {
  __shared__ float su[D];
  __shared__ float sp[S];
  __shared__ float sred[2];
  int b = blockIdx.x;
  int t = threadIdx.x;
  if (t < D) su[t] = u[b * D + t];
  __syncthreads();
  for (int hop = 0; hop < NH; ++hop) {
    const float* Gm = G + (size_t)hop * BSD + (size_t)b * S * D;
    const float* Gc = G + (size_t)(hop + 1) * BSD + (size_t)b * S * D;
    const float* ta = TA + hop * S * D;
    const float* tc = TC + hop * S * D;
    if (t < S) {
      float sc = 0.f;
      for (int d = 0; d < D; ++d) sc += (Gm[t * D + d] + ta[t * D + d]) * su[d];
      sp[t] = sc;
    }
    __syncthreads();
    if (t < 64) {
      float mx = -1e30f;
      for (int s = t; s < S; s += 64) mx = fmaxf(mx, sp[s]);
#pragma unroll
      for (int off = 1; off < 64; off <<= 1) mx = fmaxf(mx, __shfl_xor(mx, off));
      float sum = 0.f;
      for (int s = t; s < S; s += 64) sum += expf(sp[s] - mx);
#pragma unroll
      for (int off = 1; off < 64; off <<= 1) sum += __shfl_xor(sum, off);
      if (t == 0) { sred[0] = mx; sred[1] = sum; }
    }
    __syncthreads();
    float mx = sred[0];
    float inv = 1.0f / sred[1];
    if (t < S) sp[t] = expf(sp[t] - mx) * inv;
    __syncthreads();
    if (t < D) {
      float o = 0.f;
      for (int s = 0; s < S; ++s) o += sp[s] * (Gc[s * D + t] + tc[s * D + t]);
      su[t] += o;
    }
    __syncthreads();
  }
  if (t < D) u[b * D + t] = su[t];
}

__global__ __launch_bounds__(256) void k_logits_f32(
    const float* __restrict__ u, const float* __restrict__ e3,
    float* __restrict__ out) {
  __shared__ float sE[64][129];
  __shared__ float sU[64][129];
  int v0 = blockIdx.x * 64;
  int b0 = blockIdx.y * 64;
  int t = threadIdx.x;
  for (int i = 0; i < 32; ++i) {
    int lin = i * 256 + t;
    int r = lin >> 7, c = lin & 127;
    int v = v0 + r;
    sE[r][c] = (v < V) ? e3[(size_t)v * D + c] : 0.f;
    sU[r][c] = u[(b0 + r) * D + c];
  }
  __syncthreads();
  int tv = (t & 15) * 4;
  int tb = (t >> 4) * 4;
  float acc[4][4] = {};
  for (int d = 0; d < D; ++d) {
    float ev[4], ub[4];
#pragma unroll
    for (int i = 0; i < 4; ++i) ev[i] = sE[tv + i][d];
#pragma unroll
    for (int j = 0; j < 4; ++j) ub[j] = sU[tb + j][d];
#pragma unroll
    for (int j = 0; j < 4; ++j)
#pragma unroll
      for (int i = 0; i < 4; ++i) acc[j][i] += ub[j] * ev[i];
  }
  for (int j = 0; j < 4; ++j)
    for (int i = 0; i < 4; ++i) {
      int v = v0 + tv + i;
      if (v < V) out[(size_t)(b0 + tb + j) * V + v] = acc[j][i];
    }
}

extern "C" void kernel_launch(void* const* d_in, const int* in_sizes, int n_in,
                              void* d_out, int out_size, void* d_ws,
                              size_t ws_size, hipStream_t stream) {
  (void)in_sizes; (void)n_in; (void)out_size;
  const int* story = (const int*)d_in[0];
  const int* query = (const int*)d_in[1];
  const float* embs = (const float*)d_in[2];
  const float* TA = (const float*)d_in[3];
  const float* TC = (const float*)d_in[4];
  float* out = (float*)d_out;

  const size_t esm_bytes = (size_t)16 * V * 16 * 4;    // 51.2 MB
  const size_t g_bytes = (size_t)4 * BS * 64 * 4;      // 26.2 MB
  const size_t ub_bytes = (size_t)B * 64 * 4;          // 32 KB
  const size_t s16_bytes = (size_t)BS * LW * 2;        // 2.56 MB
  const size_t tp_bytes = (size_t)NH * S * 64 * 4;     // 153.6 KB each

  if (ws_size >= esm_bytes + g_bytes + ub_bytes + s16_bytes + 2 * tp_bytes) {
    char* p = (char*)d_ws;
    unsigned int* ESM = (unsigned int*)p;      p += esm_bytes;
    unsigned int* Gp = (unsigned int*)p;       p += g_bytes;
    unsigned int* ubf = (unsigned int*)p;      p += ub_bytes;
    unsigned short* story16 = (unsigned short*)p;  p += s16_bytes;
    unsigned int* TAp = (unsigned int*)p;      p += tp_bytes;
    unsigned int* TCp = (unsigned int*)p;

    k_repack<<<V / 4, 256, 0, stream>>>(embs, ESM);
    k_story16<<<BS * LW / 4 / 256, 256, 0, stream>>>(story, story16);
    k_packT<<<NH * S * 64 / 256, 256, 0, stream>>>(TA, TC, TAp, TCp);
    k_gather_slice<<<3200, 256, 0, stream>>>(story16, (const u32x4*)ESM, Gp, 0);
    k_gather_slice<<<3200, 256, 0, stream>>>(story16, (const u32x4*)ESM, Gp, 1);
    k_hops<<<B, 1024, 0, stream>>>(Gp, TAp, TCp, query, embs, ubf);
    k_logits_mfma<<<(V + 127) / 128, 256, 0, stream>>>(
        (const uint4*)ubf, (const uint4*)ESM, out);
  } else {
    float* G = (float*)d_ws;
    float* u = G + 4 * (size_t)BSD;
    k_gather_query<<<B, D, 0, stream>>>(query, embs, u);
    k_gather_story<<<B * S, D, 0, stream>>>(story, embs, G);
    k_hops_f32<<<B, 256, 0, stream>>>(G, TA, TC, u);
    k_logits_f32<<<dim3((V + 63) / 64, B / 64), 256, 0, stream>>>(
        u, embs + 3 * (size_t)VD, out);
  }
}